// Round 6
// baseline (31.291 us; speedup 1.0000x reference)
//
#include <hip/hip_runtime.h>

// Inverse 1D wavelet reconstruction, 4 levels, KS=6, PAD=1, fully fused.
// C=64, L0=16384 fixed by setup_inputs().
#define C_CH   64
#define L0     16384
#define B_OUT  4096                   // final-level outputs per block
#define NCHUNK ((L0 * 16) / B_OUT)    // 64 chunks per channel

typedef float f32x4 __attribute__((ext_vector_type(4)));
typedef float f32x2 __attribute__((ext_vector_type(2)));

struct Taps {
    float he0, he1, he2, ho0, ho1, ho2;
    float ge0, ge1, ge2, go0, go1, go2;
};

// ---------------- generic per-level routine (boundary chunks only) ----------
template <bool GLOBAL_OUT>
__device__ __forceinline__ void synth_level(
    const float* __restrict__ xp, int xlo, int Lx,
    const float* __restrict__ dp,
    float* __restrict__ yp, int ylo, int yhi,
    const Taps& T, int tid, int nthr)
{
    const int tlo = ylo >> 1, thi = yhi >> 1;
    const int tA = (tlo == 0) ? 1 : tlo;
    const int tB = (thi == Lx - 1) ? (thi - 1) : thi;

    for (int t = tA + tid; t <= tB; t += nthr) {
        const float a0 = xp[t-1-xlo], a1 = xp[t-xlo], a2 = xp[t+1-xlo];
        const float d0 = dp[t-1], d1 = dp[t], d2 = dp[t+1];
        const float ve = a0*T.he0 + a1*T.he1 + a2*T.he2 + d0*T.ge0 + d1*T.ge1 + d2*T.ge2;
        const float vo = a0*T.ho0 + a1*T.ho1 + a2*T.ho2 + d0*T.go0 + d1*T.go1 + d2*T.go2;
        *reinterpret_cast<f32x2*>(yp + (2*t - ylo)) = f32x2{ve, vo};
    }
    if (tid == 0) {
        if (tlo == 0) {  // t=0: xpad[0] = 2x0 - x1
            const float x0 = xp[0-xlo], x1 = xp[1-xlo];
            const float dd0 = dp[0], dd1 = dp[1];
            const float a0 = 2.0f*x0 - x1, b0 = 2.0f*dd0 - dd1;
            const float ve = a0*T.he0 + x0*T.he1 + x1*T.he2 + b0*T.ge0 + dd0*T.ge1 + dd1*T.ge2;
            const float vo = a0*T.ho0 + x0*T.ho1 + x1*T.ho2 + b0*T.go0 + dd0*T.go1 + dd1*T.go2;
            *reinterpret_cast<f32x2*>(yp + (0 - ylo)) = f32x2{ve, vo};
        }
        if (thi == Lx - 1) {  // t=Lx-1: xpad[Lx+1] = 2x[L-1]-x[L-2]
            const int t = Lx - 1;
            const float xm = xp[t-1-xlo], xl = xp[t-xlo];
            const float dm = dp[t-1], dl = dp[t];
            const float a2 = 2.0f*xl - xm, b2 = 2.0f*dl - dm;
            const float ve = xm*T.he0 + xl*T.he1 + a2*T.he2 + dm*T.ge0 + dl*T.ge1 + b2*T.ge2;
            const float vo = xm*T.ho0 + xl*T.ho1 + a2*T.ho2 + dm*T.go0 + dl*T.go1 + b2*T.go2;
            *reinterpret_cast<f32x2*>(yp + (2*t - ylo)) = f32x2{ve, vo};
        }
    }
}

__global__ __launch_bounds__(256) void iwt_fused_kernel(
    const float* __restrict__ sig, const float* __restrict__ d0,
    const float* __restrict__ d1,  const float* __restrict__ d2,
    const float* __restrict__ d3,  const float* __restrict__ h,
    const float* __restrict__ g,   float* __restrict__ out)
{
    const int c     = blockIdx.y;
    const int chunk = blockIdx.x;
    const int tid   = threadIdx.x;

    Taps T;
    T.he0 = h[4]; T.he1 = h[2]; T.he2 = h[0];
    T.ho0 = h[5]; T.ho1 = h[3]; T.ho2 = h[1];
    T.ge0 = g[4]; T.ge1 = g[2]; T.ge2 = g[0];
    T.go0 = g[5]; T.go1 = g[3]; T.go2 = g[1];

    __shared__ __align__(16) float s1[544];
    __shared__ __align__(16) float s2[1056];
    __shared__ __align__(16) float s3[2080];

    const int L1 = 2*L0, L2 = 4*L0, L3 = 8*L0, L4 = 16*L0;

    const float* s0p = sig + (size_t)c * L0;
    const float* d3p = d3  + (size_t)c * L0;
    const float* d2p = d2  + (size_t)c * L1;
    const float* d1p = d1  + (size_t)c * L2;
    const float* d0p = d0  + (size_t)c * L3;
    float*       outp = out + (size_t)c * L4;

    if (chunk == 0 || chunk == NCHUNK - 1) {
        // ---------------- boundary path (with barriers) --------------------
        const int lo4 = chunk * B_OUT;
        const int hi4 = lo4 + B_OUT - 1;
        int lo3 = (lo4 >> 1) - 4; if (lo3 < 0) lo3 = 0;
        int hi3 = (hi4 >> 1) + 1; if (hi3 > L3 - 1) hi3 = L3 - 1;
        int lo2 = (lo3 >> 1) - 2; if (lo2 < 0) lo2 = 0;
        int hi2 = (hi3 >> 1) + 1; if (hi2 > L2 - 1) hi2 = L2 - 1;
        int lo1 = (lo2 >> 1) - 2; if (lo1 < 0) lo1 = 0;
        int hi1 = (hi2 >> 1) + 1; if (hi1 > L1 - 1) hi1 = L1 - 1;

        synth_level<false>(s0p, 0, L0, d3p, s1, lo1, hi1, T, tid, 256);
        __syncthreads();
        synth_level<false>(s1, lo1, L1, d2p, s2, lo2, hi2, T, tid, 256);
        __syncthreads();
        synth_level<false>(s2, lo2, L2, d1p, s3, lo3, hi3, T, tid, 256);
        __syncthreads();
        synth_level<true >(s3, lo3, L3, d0p, outp + lo4, lo4, hi4, T, tid, 256);
        return;
    }

    // ------------- interior fast path: wave-independent, 0 barriers,
    // ------------- sched_barrier-enforced load/compute pipeline ------------
    const int w = tid >> 6, l = tid & 63;
    float* __restrict__ s1w = s1 + w * 136;
    float* __restrict__ s2w = s2 + w * 264;
    float* __restrict__ s3w = s3 + w * 520;

    const int T4 = ((chunk * B_OUT) >> 1) + (w << 9);
    const int T3 = T4 >> 1, T2 = T3 >> 1, T1 = T2 >> 1;
    const int ml = (l < 3) ? l : 0;   // clamp for masked tail iterations

    // ======== cluster A: issue level-1 + level-2 global loads ========
    const int t1i[2] = { T1 - 2 + l, T1 + 62 + ml };
    float xs[2][3], e3[2][3];
#pragma unroll
    for (int i = 0; i < 2; ++i) {
        const int t = t1i[i];
        xs[i][0] = s0p[t-1]; xs[i][1] = s0p[t]; xs[i][2] = s0p[t+1];
        e3[i][0] = d3p[t-1]; e3[i][1] = d3p[t]; e3[i][2] = d3p[t+1];
    }
    const int t2i[3] = { T2 - 2 + l, T2 + 62 + l, T2 + 126 + ml };
    float e2[3][3];
#pragma unroll
    for (int i = 0; i < 3; ++i) {
        const int t = t2i[i];
        e2[i][0] = d2p[t-1]; e2[i][1] = d2p[t]; e2[i][2] = d2p[t+1];
    }
    __builtin_amdgcn_sched_barrier(0);

    // ======== region 1: issue level-3 loads; compute level 1 ========
    const int t3i[5] = { T3 - 2 + l, T3 + 62 + l, T3 + 126 + l, T3 + 190 + l,
                         T3 + 254 + ml };
    float e1[5][3];
#pragma unroll
    for (int i = 0; i < 5; ++i) {
        const int t = t3i[i];
        e1[i][0] = __builtin_nontemporal_load(d1p + t - 1);
        e1[i][1] = __builtin_nontemporal_load(d1p + t);
        e1[i][2] = __builtin_nontemporal_load(d1p + t + 1);
    }
    // level 1: 67 t's in [T1-2, T1+64] -> s1w (covers x1 [T2-4, T2+129])
#pragma unroll
    for (int i = 0; i < 2; ++i) {
        const float a0 = xs[i][0], a1 = xs[i][1], a2 = xs[i][2];
        const float b0 = e3[i][0], b1 = e3[i][1], b2 = e3[i][2];
        const float ve = a0*T.he0 + a1*T.he1 + a2*T.he2 + b0*T.ge0 + b1*T.ge1 + b2*T.ge2;
        const float vo = a0*T.ho0 + a1*T.ho1 + a2*T.ho2 + b0*T.go0 + b1*T.go1 + b2*T.go2;
        if (i == 0 || l < 3)
            *reinterpret_cast<f32x2*>(s1w + (2*t1i[i] - (T2-4))) = f32x2{ve, vo};
    }
    __builtin_amdgcn_sched_barrier(0);

    // ======== region 2: issue level-4 loads; compute level 2 ========
    f32x2 e0[4][3];
#pragma unroll
    for (int i = 0; i < 4; ++i) {
        const int t0 = T4 + 2*(l + (i << 6));
        e0[i][0] = __builtin_nontemporal_load(reinterpret_cast<const f32x2*>(d0p + t0 - 2));
        e0[i][1] = __builtin_nontemporal_load(reinterpret_cast<const f32x2*>(d0p + t0));
        e0[i][2] = __builtin_nontemporal_load(reinterpret_cast<const f32x2*>(d0p + t0 + 2));
    }
    // level 2: 131 t's in [T2-2, T2+128] -> s2w (covers x2 [T3-4, T3+257])
#pragma unroll
    for (int i = 0; i < 3; ++i) {
        const int o = t2i[i] - (T2 - 4);
        const float a0 = s1w[o-1], a1 = s1w[o], a2 = s1w[o+1];
        const float b0 = e2[i][0], b1 = e2[i][1], b2 = e2[i][2];
        const float ve = a0*T.he0 + a1*T.he1 + a2*T.he2 + b0*T.ge0 + b1*T.ge1 + b2*T.ge2;
        const float vo = a0*T.ho0 + a1*T.ho1 + a2*T.ho2 + b0*T.go0 + b1*T.go1 + b2*T.go2;
        if (i < 2 || l < 3)
            *reinterpret_cast<f32x2*>(s2w + (2*t2i[i] - (T3-4))) = f32x2{ve, vo};
    }
    __builtin_amdgcn_sched_barrier(0);

    // ======== region 3: compute level 3 then level 4 ========
#pragma unroll
    for (int i = 0; i < 5; ++i) {
        const int o = t3i[i] - (T3 - 4);
        const float a0 = s2w[o-1], a1 = s2w[o], a2 = s2w[o+1];
        const float b0 = e1[i][0], b1 = e1[i][1], b2 = e1[i][2];
        const float ve = a0*T.he0 + a1*T.he1 + a2*T.he2 + b0*T.ge0 + b1*T.ge1 + b2*T.ge2;
        const float vo = a0*T.ho0 + a1*T.ho1 + a2*T.ho2 + b0*T.go0 + b1*T.go1 + b2*T.go2;
        if (i < 4 || l < 3)
            *reinterpret_cast<f32x2*>(s3w + (2*t3i[i] - (T4-4))) = f32x2{ve, vo};
    }
#pragma unroll
    for (int i = 0; i < 4; ++i) {
        const int t0 = T4 + 2*(l + (i << 6));
        const int o  = t0 - (T4 - 4);
        const float a0 = s3w[o-1], a1 = s3w[o], a2 = s3w[o+1], a3 = s3w[o+2];
        const float b0 = e0[i][0].y, b1 = e0[i][1].x, b2 = e0[i][1].y, b3 = e0[i][2].x;
        f32x4 v;
        v.x = a0*T.he0 + a1*T.he1 + a2*T.he2 + b0*T.ge0 + b1*T.ge1 + b2*T.ge2;
        v.y = a0*T.ho0 + a1*T.ho1 + a2*T.ho2 + b0*T.go0 + b1*T.go1 + b2*T.go2;
        v.z = a1*T.he0 + a2*T.he1 + a3*T.he2 + b1*T.ge0 + b2*T.ge1 + b3*T.ge2;
        v.w = a1*T.ho0 + a2*T.ho1 + a3*T.ho2 + b1*T.go0 + b2*T.go1 + b3*T.go2;
        __builtin_nontemporal_store(v, reinterpret_cast<f32x4*>(outp + 2*t0));
    }
}

extern "C" void kernel_launch(void* const* d_in, const int* in_sizes, int n_in,
                              void* d_out, int out_size, void* d_ws, size_t ws_size,
                              hipStream_t stream) {
    const float* sig = (const float*)d_in[0];
    const float* d0  = (const float*)d_in[1];
    const float* d1  = (const float*)d_in[2];
    const float* d2  = (const float*)d_in[3];
    const float* d3  = (const float*)d_in[4];
    const float* h   = (const float*)d_in[5];
    const float* g   = (const float*)d_in[6];
    float* out = (float*)d_out;

    dim3 grid(NCHUNK, C_CH);
    iwt_fused_kernel<<<grid, 256, 0, stream>>>(sig, d0, d1, d2, d3, h, g, out);
}

// Round 7
// 29.034 us; speedup vs baseline: 1.0778x; 1.0778x over previous
//
#include <hip/hip_runtime.h>

// Inverse 1D wavelet reconstruction, 4 levels, KS=6, PAD=1, fully fused.
// C=64, L0=16384 fixed by setup_inputs().
#define C_CH   64
#define L0     16384
#define B_OUT  4096                   // final-level outputs per block
#define NCHUNK ((L0 * 16) / B_OUT)    // 64 chunks per channel

typedef float f32x4 __attribute__((ext_vector_type(4)));
typedef float f32x2 __attribute__((ext_vector_type(2)));

struct Taps {
    float he0, he1, he2, ho0, ho1, ho2;
    float ge0, ge1, ge2, go0, go1, go2;
};

// ---------------- generic per-level routine (boundary chunks only) ----------
template <bool GLOBAL_OUT>
__device__ __forceinline__ void synth_level(
    const float* __restrict__ xp, int xlo, int Lx,
    const float* __restrict__ dp,
    float* __restrict__ yp, int ylo, int yhi,
    const Taps& T, int tid, int nthr)
{
    const int tlo = ylo >> 1, thi = yhi >> 1;
    const int tA = (tlo == 0) ? 1 : tlo;
    const int tB = (thi == Lx - 1) ? (thi - 1) : thi;

    for (int t = tA + tid; t <= tB; t += nthr) {
        const float a0 = xp[t-1-xlo], a1 = xp[t-xlo], a2 = xp[t+1-xlo];
        const float d0 = dp[t-1], d1 = dp[t], d2 = dp[t+1];
        const float ve = a0*T.he0 + a1*T.he1 + a2*T.he2 + d0*T.ge0 + d1*T.ge1 + d2*T.ge2;
        const float vo = a0*T.ho0 + a1*T.ho1 + a2*T.ho2 + d0*T.go0 + d1*T.go1 + d2*T.go2;
        *reinterpret_cast<f32x2*>(yp + (2*t - ylo)) = f32x2{ve, vo};
    }
    if (tid == 0) {
        if (tlo == 0) {  // t=0: xpad[0] = 2x0 - x1
            const float x0 = xp[0-xlo], x1 = xp[1-xlo];
            const float dd0 = dp[0], dd1 = dp[1];
            const float a0 = 2.0f*x0 - x1, b0 = 2.0f*dd0 - dd1;
            const float ve = a0*T.he0 + x0*T.he1 + x1*T.he2 + b0*T.ge0 + dd0*T.ge1 + dd1*T.ge2;
            const float vo = a0*T.ho0 + x0*T.ho1 + x1*T.ho2 + b0*T.go0 + dd0*T.go1 + dd1*T.go2;
            *reinterpret_cast<f32x2*>(yp + (0 - ylo)) = f32x2{ve, vo};
        }
        if (thi == Lx - 1) {  // t=Lx-1: xpad[Lx+1] = 2x[L-1]-x[L-2]
            const int t = Lx - 1;
            const float xm = xp[t-1-xlo], xl = xp[t-xlo];
            const float dm = dp[t-1], dl = dp[t];
            const float a2 = 2.0f*xl - xm, b2 = 2.0f*dl - dm;
            const float ve = xm*T.he0 + xl*T.he1 + a2*T.he2 + dm*T.ge0 + dl*T.ge1 + b2*T.ge2;
            const float vo = xm*T.ho0 + xl*T.ho1 + a2*T.ho2 + dm*T.go0 + dl*T.go1 + b2*T.go2;
            *reinterpret_cast<f32x2*>(yp + (2*t - ylo)) = f32x2{ve, vo};
        }
    }
}

// ---------------- interior fast level: 1 aligned f32x2 load per lane + -----
// ---------------- __shfl halo exchange (edge lanes do 4B predicated loads) --
// Preconditions (interior chunks): ylo % 4 == 0, tlo > 0, thi < Lx-1.
template <bool GLOBAL_OUT, bool X_GLOBAL>
__device__ __forceinline__ void synth_level_int(
    const float* __restrict__ xp, int xlo,
    const float* __restrict__ dp,
    float* __restrict__ yp, int ylo, int yhi,
    const Taps& T, int tid, int nthr)
{
    const int tlo = ylo >> 1, thi = yhi >> 1;     // tlo even
    const int tV0 = tlo;
    const int tVmax = thi - 1;
    const int nvec  = ((tVmax - tV0) >> 1) + 1;
    const int nfull = nvec & ~(nthr - 1);         // full-wave rounds only
    const int l = tid & 63;

    // full rounds: every lane active -> shuffles valid
    for (int i = tid; i < nfull; i += nthr) {
        const int t0 = tV0 + 2 * i;               // even, aligned
        const f32x2 b = *reinterpret_cast<const f32x2*>(dp + t0);
        float dm = __shfl_up(b.y, 1, 64);         // d[t0-1] from lane l-1
        float dn = __shfl_down(b.x, 1, 64);       // d[t0+2] from lane l+1
        if (l == 0)  dm = dp[t0 - 1];
        if (l == 63) dn = dp[t0 + 2];
        float a0, a1, a2, a3;
        if (X_GLOBAL) {
            const f32x2 a = *reinterpret_cast<const f32x2*>(xp + t0);
            float am = __shfl_up(a.y, 1, 64);
            float an = __shfl_down(a.x, 1, 64);
            if (l == 0)  am = xp[t0 - 1];
            if (l == 63) an = xp[t0 + 2];
            a0 = am; a1 = a.x; a2 = a.y; a3 = an;
        } else {
            const int o = t0 - xlo;
            a0 = xp[o-1]; a1 = xp[o]; a2 = xp[o+1]; a3 = xp[o+2];
        }
        f32x4 v;
        v.x = a0*T.he0 + a1*T.he1 + a2*T.he2 + dm *T.ge0 + b.x*T.ge1 + b.y*T.ge2;
        v.y = a0*T.ho0 + a1*T.ho1 + a2*T.ho2 + dm *T.go0 + b.x*T.go1 + b.y*T.go2;
        v.z = a1*T.he0 + a2*T.he1 + a3*T.he2 + b.x*T.ge0 + b.y*T.ge1 + dn *T.ge2;
        v.w = a1*T.ho0 + a2*T.ho1 + a3*T.ho2 + b.x*T.go0 + b.y*T.go1 + dn *T.go2;
        f32x4* dst = reinterpret_cast<f32x4*>(yp + (2*t0 - ylo));   // 16B aligned
        if (GLOBAL_OUT) __builtin_nontemporal_store(v, dst);
        else            *dst = v;
    }

    // partial round (some lanes inactive -> no shuffles): direct loads
    for (int i = nfull + tid; i < nvec; i += nthr) {
        const int t0 = tV0 + 2 * i;
        const float dm = dp[t0-1], dc = dp[t0], dd = dp[t0+1], dn = dp[t0+2];
        const int o = t0 - xlo;                   // X_GLOBAL passes xlo=0
        const float a0 = xp[o-1], a1 = xp[o], a2 = xp[o+1], a3 = xp[o+2];
        f32x4 v;
        v.x = a0*T.he0 + a1*T.he1 + a2*T.he2 + dm*T.ge0 + dc*T.ge1 + dd*T.ge2;
        v.y = a0*T.ho0 + a1*T.ho1 + a2*T.ho2 + dm*T.go0 + dc*T.go1 + dd*T.go2;
        v.z = a1*T.he0 + a2*T.he1 + a3*T.he2 + dc*T.ge0 + dd*T.ge1 + dn*T.ge2;
        v.w = a1*T.ho0 + a2*T.ho1 + a3*T.ho2 + dc*T.go0 + dd*T.go1 + dn*T.go2;
        f32x4* dst = reinterpret_cast<f32x4*>(yp + (2*t0 - ylo));
        if (GLOBAL_OUT) __builtin_nontemporal_store(v, dst);
        else            *dst = v;
    }

    // scalar tail: at most one t position
    for (int t = tV0 + 2*nvec + tid; t <= thi; t += nthr) {
        const int o = t - xlo;
        const float a0 = xp[o-1], a1 = xp[o], a2 = xp[o+1];
        const float dm = dp[t-1], dc = dp[t], dn = dp[t+1];
        const float ve = a0*T.he0 + a1*T.he1 + a2*T.he2 + dm*T.ge0 + dc*T.ge1 + dn*T.ge2;
        const float vo = a0*T.ho0 + a1*T.ho1 + a2*T.ho2 + dm*T.go0 + dc*T.go1 + dn*T.go2;
        *reinterpret_cast<f32x2*>(yp + (2*t - ylo)) = f32x2{ve, vo};
    }
}

__global__ __launch_bounds__(256) void iwt_fused_kernel(
    const float* __restrict__ sig, const float* __restrict__ d0,
    const float* __restrict__ d1,  const float* __restrict__ d2,
    const float* __restrict__ d3,  const float* __restrict__ h,
    const float* __restrict__ g,   float* __restrict__ out)
{
    const int c     = blockIdx.y;
    const int chunk = blockIdx.x;
    const int tid   = threadIdx.x;

    Taps T;
    T.he0 = h[4]; T.he1 = h[2]; T.he2 = h[0];
    T.ho0 = h[5]; T.ho1 = h[3]; T.ho2 = h[1];
    T.ge0 = g[4]; T.ge1 = g[2]; T.ge2 = g[0];
    T.go0 = g[5]; T.go1 = g[3]; T.go2 = g[1];

    __shared__ __align__(16) float s1[544];
    __shared__ __align__(16) float s2[1056];
    __shared__ __align__(16) float s3[2080];

    const int L1 = 2*L0, L2 = 4*L0, L3 = 8*L0, L4 = 16*L0;

    const float* s0p = sig + (size_t)c * L0;
    const float* d3p = d3  + (size_t)c * L0;
    const float* d2p = d2  + (size_t)c * L1;
    const float* d1p = d1  + (size_t)c * L2;
    const float* d0p = d0  + (size_t)c * L3;
    float*       outp = out + (size_t)c * L4;

    const int lo4 = chunk * B_OUT;
    const int hi4 = lo4 + B_OUT - 1;
    int lo3 = (lo4 >> 1) - 4; if (lo3 < 0) lo3 = 0;
    int hi3 = (hi4 >> 1) + 1; if (hi3 > L3 - 1) hi3 = L3 - 1;
    int lo2 = (lo3 >> 1) - 2; if (lo2 < 0) lo2 = 0;
    int hi2 = (hi3 >> 1) + 1; if (hi2 > L2 - 1) hi2 = L2 - 1;
    int lo1 = (lo2 >> 1) - 2; if (lo1 < 0) lo1 = 0;
    int hi1 = (hi2 >> 1) + 1; if (hi1 > L1 - 1) hi1 = L1 - 1;

    if (chunk == 0 || chunk == NCHUNK - 1) {
        // boundary path: generic (handles antireflect pad formulas)
        synth_level<false>(s0p, 0, L0, d3p, s1, lo1, hi1, T, tid, 256);
        __syncthreads();
        synth_level<false>(s1, lo1, L1, d2p, s2, lo2, hi2, T, tid, 256);
        __syncthreads();
        synth_level<false>(s2, lo2, L2, d1p, s3, lo3, hi3, T, tid, 256);
        __syncthreads();
        synth_level<true >(s3, lo3, L3, d0p, outp + lo4, lo4, hi4, T, tid, 256);
        return;
    }

    // interior path: aligned loads + shuffle halo exchange
    synth_level_int<false, true >(s0p, 0,   d3p, s1, lo1, hi1, T, tid, 256);
    __syncthreads();
    synth_level_int<false, false>(s1,  lo1, d2p, s2, lo2, hi2, T, tid, 256);
    __syncthreads();
    synth_level_int<false, false>(s2,  lo2, d1p, s3, lo3, hi3, T, tid, 256);
    __syncthreads();
    synth_level_int<true , false>(s3,  lo3, d0p, outp + lo4, lo4, hi4, T, tid, 256);
}

extern "C" void kernel_launch(void* const* d_in, const int* in_sizes, int n_in,
                              void* d_out, int out_size, void* d_ws, size_t ws_size,
                              hipStream_t stream) {
    const float* sig = (const float*)d_in[0];
    const float* d0  = (const float*)d_in[1];
    const float* d1  = (const float*)d_in[2];
    const float* d2  = (const float*)d_in[3];
    const float* d3  = (const float*)d_in[4];
    const float* h   = (const float*)d_in[5];
    const float* g   = (const float*)d_in[6];
    float* out = (float*)d_out;

    dim3 grid(NCHUNK, C_CH);
    iwt_fused_kernel<<<grid, 256, 0, stream>>>(sig, d0, d1, d2, d3, h, g, out);
}